// Round 1
// baseline (5803.199 us; speedup 1.0000x reference)
//
#include <hip/hip_runtime.h>
#include <cstddef>

#define BATCH  32768
#define T      11
#define INDIM  2
#define H      64
#define STEPS  80

__device__ __forceinline__ float sigmoidf_(float x) {
    float e = __expf(-x);
    return __fdividef(1.0f, 1.0f + e);
}

__device__ __forceinline__ float tanhf_(float x) {
    float e = __expf(-2.0f * x);
    return __fdividef(1.0f - e, 1.0f + e);
}

// One GRU cell for 64 rows (lane = row), gates split across 4 waves (16 j's each).
// hreg: this thread's register copy of the hidden state (pre-cell), used for matvec.
// hlds: transposed authoritative LDS copy hlds[k*64 + lane]; updated in place
//       (each (jj,lane) slot touched by exactly one thread -> no race).
template<int KIN>
__device__ __forceinline__ void gru_cell(
    const float* __restrict__ Wih, const float* __restrict__ Whh,
    const float* __restrict__ bih, const float* __restrict__ bhh,
    const float (&xin)[KIN], const float (&hreg)[64],
    float* __restrict__ hlds, int lane, int wv)
{
    #pragma unroll 1
    for (int u = 0; u < 16; ++u) {
        const int jj = wv * 16 + u;                 // wave-uniform
        float ar  = bih[jj]       + bhh[jj];
        float az  = bih[jj + 64]  + bhh[jj + 64];
        float ani = bih[jj + 128];
        float anh = bhh[jj + 128];
        const float* __restrict__ wi = Wih + jj * KIN;
        #pragma unroll
        for (int k = 0; k < KIN; ++k) {
            ar  += xin[k] * wi[k];
            az  += xin[k] * wi[64 * KIN + k];
            ani += xin[k] * wi[128 * KIN + k];
        }
        const float* __restrict__ wh = Whh + jj * 64;
        #pragma unroll
        for (int k = 0; k < 64; ++k) {
            ar  += hreg[k] * wh[k];
            az  += hreg[k] * wh[64 * 64 + k];
            anh += hreg[k] * wh[128 * 64 + k];
        }
        const float r = sigmoidf_(ar);
        const float z = sigmoidf_(az);
        const float n = tanhf_(ani + r * anh);
        const float hold = hlds[jj * 64 + lane];
        hlds[jj * 64 + lane] = (1.0f - z) * n + z * hold;
    }
}

__global__ __launch_bounds__(256, 2)
void gru_traj_kernel(
    const float* __restrict__ x,
    const float* __restrict__ eWih0, const float* __restrict__ eWhh0,
    const float* __restrict__ ebih0, const float* __restrict__ ebhh0,
    const float* __restrict__ eWih1, const float* __restrict__ eWhh1,
    const float* __restrict__ ebih1, const float* __restrict__ ebhh1,
    const float* __restrict__ dWih0, const float* __restrict__ dWhh0,
    const float* __restrict__ dbih0, const float* __restrict__ dbhh0,
    const float* __restrict__ dWih1, const float* __restrict__ dWhh1,
    const float* __restrict__ dbih1, const float* __restrict__ dbhh1,
    const float* __restrict__ fcW,  const float* __restrict__ fcb,
    float* __restrict__ out)
{
    __shared__ float h0s[64 * 64];   // [k][lane] transposed
    __shared__ float h1s[64 * 64];

    const int tid  = threadIdx.x;
    const int lane = tid & 63;
    const int wv   = __builtin_amdgcn_readfirstlane(tid >> 6);
    const int row  = blockIdx.x * 64 + lane;

    for (int i = tid; i < 64 * 64; i += 256) { h0s[i] = 0.0f; h1s[i] = 0.0f; }

    float h0r[64], h1r[64];
    #pragma unroll
    for (int k = 0; k < 64; ++k) { h0r[k] = 0.0f; h1r[k] = 0.0f; }
    __syncthreads();

    const float* __restrict__ xrow = x + (size_t)row * (T * INDIM);
    float xin[2];

    // ---------------- encoder ----------------
    for (int t = 0; t < T; ++t) {
        float2 xv = *(const float2*)(xrow + t * INDIM);
        xin[0] = xv.x; xin[1] = xv.y;

        gru_cell<2>(eWih0, eWhh0, ebih0, ebhh0, xin, h0r, h0s, lane, wv);
        __syncthreads();
        #pragma unroll
        for (int k = 0; k < 64; ++k) h0r[k] = h0s[k * 64 + lane];
        __syncthreads();

        gru_cell<64>(eWih1, eWhh1, ebih1, ebhh1, h0r, h1r, h1s, lane, wv);
        __syncthreads();
        #pragma unroll
        for (int k = 0; k < 64; ++k) h1r[k] = h1s[k * 64 + lane];
        __syncthreads();
    }

    // ---------------- decoder ----------------
    {
        float2 xl = *(const float2*)(xrow + (T - 1) * INDIM);
        xin[0] = xl.x; xin[1] = xl.y;
    }
    float* __restrict__ outrow = out + (size_t)row * (STEPS * INDIM);

    for (int s = 0; s < STEPS; ++s) {
        gru_cell<2>(dWih0, dWhh0, dbih0, dbhh0, xin, h0r, h0s, lane, wv);
        __syncthreads();
        #pragma unroll
        for (int k = 0; k < 64; ++k) h0r[k] = h0s[k * 64 + lane];
        __syncthreads();

        gru_cell<64>(dWih1, dWhh1, dbih1, dbhh1, h0r, h1r, h1s, lane, wv);
        __syncthreads();
        #pragma unroll
        for (int k = 0; k < 64; ++k) h1r[k] = h1s[k * 64 + lane];
        __syncthreads();

        float p0 = fcb[0], p1 = fcb[1];
        #pragma unroll
        for (int k = 0; k < 64; ++k) {
            p0 += h1r[k] * fcW[k];
            p1 += h1r[k] * fcW[64 + k];
        }
        xin[0] = p0; xin[1] = p1;
        if (wv == 0) {
            *(float2*)(outrow + s * INDIM) = make_float2(p0, p1);
        }
    }
}

extern "C" void kernel_launch(void* const* d_in, const int* in_sizes, int n_in,
                              void* d_out, int out_size, void* d_ws, size_t ws_size,
                              hipStream_t stream) {
    (void)n_in; (void)out_size; (void)d_ws; (void)ws_size;

    const float* x     = (const float*)d_in[0];
    const float* eWih0 = (const float*)d_in[1];
    const float* eWhh0 = (const float*)d_in[2];
    const float* ebih0 = (const float*)d_in[3];
    const float* ebhh0 = (const float*)d_in[4];
    const float* eWih1 = (const float*)d_in[5];
    const float* eWhh1 = (const float*)d_in[6];
    const float* ebih1 = (const float*)d_in[7];
    const float* ebhh1 = (const float*)d_in[8];
    const float* dWih0 = (const float*)d_in[9];
    const float* dWhh0 = (const float*)d_in[10];
    const float* dbih0 = (const float*)d_in[11];
    const float* dbhh0 = (const float*)d_in[12];
    const float* dWih1 = (const float*)d_in[13];
    const float* dWhh1 = (const float*)d_in[14];
    const float* dbih1 = (const float*)d_in[15];
    const float* dbhh1 = (const float*)d_in[16];
    const float* fcW   = (const float*)d_in[17];
    const float* fcb   = (const float*)d_in[18];
    float* out = (float*)d_out;

    const int b = in_sizes[0] / (T * INDIM);   // 32768
    dim3 grid(b / 64), block(256);
    hipLaunchKernelGGL(gru_traj_kernel, grid, block, 0, stream,
        x, eWih0, eWhh0, ebih0, ebhh0, eWih1, eWhh1, ebih1, ebhh1,
        dWih0, dWhh0, dbih0, dbhh0, dWih1, dWhh1, dbih1, dbhh1,
        fcW, fcb, out);
}